// Round 1
// 116.089 us; speedup vs baseline: 1.0590x; 1.0590x over previous
//
#include <hip/hip_runtime.h>

#define Wd 64
#define Hd 64
#define HWp 4096
#define CIN_ 128
#define COUT_ 128

typedef _Float16 f16;
typedef _Float16 h2    __attribute__((ext_vector_type(2)));
typedef _Float16 f16x8 __attribute__((ext_vector_type(8)));
typedef float f32x4    __attribute__((ext_vector_type(4)));

__device__ inline ushort f2h(float f) {
    f16 h = (f16)f;
    return __builtin_bit_cast(ushort, h);
}
__device__ inline h2 gb(const int4& g, int d) {
    return __builtin_bit_cast(h2, (&g.x)[d]);
}
__device__ inline h2 dup(float f) {
    f16 h = (f16)f;
    h2 r; r[0] = h; r[1] = h;
    return r;
}
struct H8 { h2 r[4]; };

// ---------------------------------------------------------------------------
// K_prep (1344 blocks):
//   blk 0..255    : transpose x NCHW f32 -> xt[b][yx][c] f16
//   blk 256..831  : repack main w -> f16 w_t2 in MFMA A-fragment order
//   blk 832..1343 : offset conv (4 used ch) -> der[b][p] = {sy,sx,sc1,sc2}
//                   (bilinear meta now computed inline in the GEMM kernel)
// ---------------------------------------------------------------------------
__global__ __launch_bounds__(256) void prep_offsets_kernel(
    const float* __restrict__ x, const float* __restrict__ w,
    const float* __restrict__ w_off, const float* __restrict__ b_off,
    ushort* __restrict__ xt, ushort* __restrict__ w_t2,
    float4* __restrict__ der)
{
    __shared__ char smem[34816];
    int blk = blockIdx.x;
    int t = threadIdx.x;

    if (blk < 256) {
        ushort* tile = (ushort*)smem;                 // [128][136]
        int b = blk >> 5, yx0 = (blk & 31) << 7;
        const float* xb = x + (size_t)b * CIN_ * HWp + yx0;
        int lanelo = t & 31, grp = t >> 5;
        #pragma unroll
        for (int i = 0; i < 4; i++) {
            int cbase = i * 32 + grp * 4;
            float4 v0 = *(const float4*)(xb + (size_t)(cbase + 0) * HWp + lanelo * 4);
            float4 v1 = *(const float4*)(xb + (size_t)(cbase + 1) * HWp + lanelo * 4);
            float4 v2 = *(const float4*)(xb + (size_t)(cbase + 2) * HWp + lanelo * 4);
            float4 v3 = *(const float4*)(xb + (size_t)(cbase + 3) * HWp + lanelo * 4);
            ushort4 u;
            u.x = f2h(v0.x); u.y = f2h(v1.x); u.z = f2h(v2.x); u.w = f2h(v3.x);
            *(ushort4*)&tile[(lanelo * 4 + 0) * 136 + cbase] = u;
            u.x = f2h(v0.y); u.y = f2h(v1.y); u.z = f2h(v2.y); u.w = f2h(v3.y);
            *(ushort4*)&tile[(lanelo * 4 + 1) * 136 + cbase] = u;
            u.x = f2h(v0.z); u.y = f2h(v1.z); u.z = f2h(v2.z); u.w = f2h(v3.z);
            *(ushort4*)&tile[(lanelo * 4 + 2) * 136 + cbase] = u;
            u.x = f2h(v0.w); u.y = f2h(v1.w); u.z = f2h(v2.w); u.w = f2h(v3.w);
            *(ushort4*)&tile[(lanelo * 4 + 3) * 136 + cbase] = u;
        }
        __syncthreads();
        ushort* dst = xt + ((size_t)b * HWp + yx0) * CIN_;
        int c8 = (t & 15) * 8, yxg = t >> 4;
        #pragma unroll
        for (int i = 0; i < 8; i++) {
            int yxl = i * 16 + yxg;
            int4 v = *(int4*)&tile[yxl * 136 + c8];
            *(int4*)(dst + (size_t)yxl * CIN_ + c8) = v;
        }
    } else if (blk < 832) {
        int i = (blk - 256) * 256 + t;               // 147456 total
        int j    = i & 7;
        int lane = (i >> 3) & 63;
        int ii   = (i >> 9) & 3;
        int wm   = (i >> 11) & 1;
        int s    = i >> 12;
        int o = wm * 64 + ii * 16 + (lane & 15);
        int c = (s & 3) * 32 + (lane >> 4) * 8 + j;
        int k = s >> 2;
        w_t2[i] = f2h(w[o * 1152 + c * 9 + k]);
    } else {
        float* wl   = (float*)smem;                   // 4608 f
        float* part = (float*)(smem + 18432);         // 1024 f
        int blk2 = blk - 832;
        int b = blk2 >> 6;
        int h = blk2 & 63;

        for (int i = t; i < 4608; i += 256) {
            int j = i / 1152;
            int r = i - j * 1152;                     // c*9 + tap
            wl[r * 4 + j] = w_off[i];
        }
        __syncthreads();

        int pi = t & 63, cc = t >> 6;
        const float* xb = x + (size_t)(b * CIN_ + cc * 32) * HWp;

        int idx9[9];
        float msk9[9];
        #pragma unroll
        for (int dy = 0; dy < 3; dy++) {
            int hy = h + dy - 1;
            int hyc = min(max(hy, 0), Hd - 1);
            bool vr = (hy >= 0) && (hy < Hd);
            #pragma unroll
            for (int dx = 0; dx < 3; dx++) {
                int wx = pi + dx - 1;
                int wxc = min(max(wx, 0), Wd - 1);
                bool v = vr && (wx >= 0) && (wx < Wd);
                idx9[dy * 3 + dx] = hyc * Wd + wxc;
                msk9[dy * 3 + dx] = v ? 1.0f : 0.0f;
            }
        }

        float o0 = 0.f, o1 = 0.f, o2 = 0.f, o3 = 0.f;
        #pragma unroll 2
        for (int c = 0; c < 32; c++) {
            const float* xp = xb + c * HWp;
            const float* wc = &wl[(cc * 32 + c) * 36];
            float xv[9];
            #pragma unroll
            for (int tp = 0; tp < 9; tp++) xv[tp] = xp[idx9[tp]] * msk9[tp];
            #pragma unroll
            for (int tp = 0; tp < 9; tp++) {
                float4 wj = *(const float4*)&wc[tp * 4];
                o0 += xv[tp] * wj.x; o1 += xv[tp] * wj.y;
                o2 += xv[tp] * wj.z; o3 += xv[tp] * wj.w;
            }
        }
        part[t * 4 + 0] = o0;
        part[t * 4 + 1] = o1;
        part[t * 4 + 2] = o2;
        part[t * 4 + 3] = o3;
        __syncthreads();

        if (t < 64) {
            float s0 = b_off[0], s1 = b_off[1], s2 = b_off[2], s3 = b_off[3];
            #pragma unroll
            for (int q = 0; q < 4; q++) {
                s0 += part[(q * 64 + t) * 4 + 0];
                s1 += part[(q * 64 + t) * 4 + 1];
                s2 += part[(q * 64 + t) * 4 + 2];
                s3 += part[(q * 64 + t) * 4 + 3];
            }
            float4 d;
            d.x = s0;
            d.y = s1;
            d.z = fmaxf(s2, 0.f) + 1.f;
            d.w = fmaxf(s3, 0.f) + 1.f;
            der[(size_t)b * HWp + h * Wd + t] = d;
        }
    }
}

// ---------------------------------------------------------------------------
// K3: fused gather + f16 MFMA GEMM, BK=64 stages, depth-2 gather prefetch.
// Block = (b, 2 h-rows): M=128(o), N=128(p), K=1152 in 18 stages.
// 512 thr = 8 waves (2 wm x 4 ns), wave tile 64x32.
// Pipeline per stage st:
//   stageA(st+1) [2 global_load_lds, issued FIRST]
//   issue gathers for st+2 [8 int4 loads, meta computed inline from der]
//   MFMA(st)  -> commitS(st+1) [waits only its own gathers, issued st-1]
//   s_waitcnt vmcnt(8) lgkmcnt(0)  (A-staging drained; st+2 gathers stay
//   in flight ACROSS the raw s_barrier)  -- counted-vmcnt, never drain-0.
// ---------------------------------------------------------------------------
__global__ __launch_bounds__(512, 1) void deform_gemm_mfma(
    const ushort* __restrict__ xt, const ushort* __restrict__ w_t2,
    const float* __restrict__ bias, const float4* __restrict__ der,
    float* __restrict__ out)
{
    __shared__ ushort A_lds[2][2][4096];      // [buf][chunk][ (wm*4+i)*512 + lane*8 + j ]
    __shared__ ushort S_lds[2][2][128 * 40];  // [buf][chunk][ p*40 + c8 ]

    int t = threadIdx.x;
    int b = blockIdx.x >> 5;
    int rp = blockIdx.x & 31;
    int p0 = rp << 7;
    const ushort* xtb = xt + (size_t)b * HWp * CIN_;

    int p  = t >> 2;                 // 0..127 position in tile
    int c8 = (t & 3) << 3;           // channel offset in 32-chunk

    int wv = t >> 6, lane = t & 63;
    int wm = wv & 1, ns = wv >> 1;   // M-half, N-32-seg (0..3)
    int lm = lane & 15, lq = lane >> 4;

    f32x4 acc[4][2] = {};

    int pg = p0 + p;
    float fh = (float)(pg >> 6), fp = (float)(pg & 63);
    float4 dv = der[(size_t)b * HWp + pg];   // {sy, sx, sc1, sc2}

    const ushort* cbp[4];

    // inline bilinear metadata for tap k (replaces midx/mw memory round-trip)
    auto computeMeta = [&](int k, h2 (&cw)[4]) {
        int ky = (k * 11) >> 5;              // k/3 for k in 0..8
        int kx = k - ky * 3;
        float by = (float)(ky - 1), bx = (float)(kx - 1);
        bool corner = (ky != 1) && (kx != 1);
        bool edge = (ky != 1) ^ (kx != 1);
        float sk = corner ? dv.z : (edge ? dv.w : 0.0f);
        float py = fh + by * sk + dv.x;
        float px = fp + bx * sk + dv.y;
        float y0f = floorf(py), x0f = floorf(px);
        float wy = py - y0f, wx = px - x0f;
        int y0 = (int)y0f, x0 = (int)x0f;
        int y1 = y0 + 1, x1 = x0 + 1;
        float vy0 = (y0 >= 0 && y0 < Hd) ? 1.f : 0.f;
        float vy1 = (y1 >= 0 && y1 < Hd) ? 1.f : 0.f;
        float vx0 = (x0 >= 0 && x0 < Wd) ? 1.f : 0.f;
        float vx1 = (x1 >= 0 && x1 < Wd) ? 1.f : 0.f;
        int cy0 = min(max(y0, 0), Hd - 1), cy1 = min(max(y1, 0), Hd - 1);
        int cx0 = min(max(x0, 0), Wd - 1), cx1 = min(max(x1, 0), Wd - 1);
        cbp[0] = xtb + (cy0 * Wd + cx0) * CIN_ + c8;
        cbp[1] = xtb + (cy0 * Wd + cx1) * CIN_ + c8;
        cbp[2] = xtb + (cy1 * Wd + cx0) * CIN_ + c8;
        cbp[3] = xtb + (cy1 * Wd + cx1) * CIN_ + c8;
        cw[0] = dup((1.f - wy) * (1.f - wx) * vy0 * vx0);
        cw[1] = dup((1.f - wy) * wx * vy0 * vx1);
        cw[2] = dup(wy * (1.f - wx) * vy1 * vx0);
        cw[3] = dup(wy * wx * vy1 * vx1);
    };

    // async A staging: stage st covers w_t2 ushorts [st*8192, st*8192+8192)
    auto stageA = [&](int buf, int st) {
        const ushort* src = w_t2 + (size_t)st * 8192;
        #pragma unroll
        for (int cc = 0; cc < 2; cc++) {
            const ushort* g = src + cc * 4096 + wv * 512 + lane * 8;
            ushort* l = &A_lds[buf][cc][wv * 512];
            __builtin_amdgcn_global_load_lds(
                (const __attribute__((address_space(1))) unsigned int*)g,
                (__attribute__((address_space(3))) unsigned int*)l, 16, 0, 0);
        }
    };

    auto issue = [&](int st, int4 (&G)[2][4]) {
        #pragma unroll
        for (int cc = 0; cc < 2; cc++) {
            int q = (2 * st + cc) & 3;
            #pragma unroll
            for (int r = 0; r < 4; r++)
                G[cc][r] = *(const int4*)(cbp[r] + q * 32);
        }
    };
    auto commitS = [&](int buf, const int4 (&G)[2][4], const h2 (&cw)[4]) {
        #pragma unroll
        for (int cc = 0; cc < 2; cc++) {
            H8 tmp;
            #pragma unroll
            for (int d = 0; d < 4; d++) {
                h2 r = gb(G[cc][0], d) * cw[0];
                r = gb(G[cc][1], d) * cw[1] + r;
                r = gb(G[cc][2], d) * cw[2] + r;
                r = gb(G[cc][3], d) * cw[3] + r;
                tmp.r[d] = r;
            }
            *(int4*)&S_lds[buf][cc][p * 40 + c8] = __builtin_bit_cast(int4, tmp);
        }
    };
    auto mfmaSec = [&](int cur) {
        #pragma unroll
        for (int cc = 0; cc < 2; cc++) {
            f16x8 af[4], bfr[2];
            #pragma unroll
            for (int i = 0; i < 4; i++)
                af[i] = *(const f16x8*)&A_lds[cur][cc][(wm * 4 + i) * 512 + lane * 8];
            #pragma unroll
            for (int f = 0; f < 2; f++)
                bfr[f] = *(const f16x8*)&S_lds[cur][cc][(ns * 32 + f * 16 + lm) * 40 + lq * 8];
            #pragma unroll
            for (int i = 0; i < 4; i++)
                #pragma unroll
                for (int f = 0; f < 2; f++)
                    acc[i][f] = __builtin_amdgcn_mfma_f32_16x16x32_f16(
                        af[i], bfr[f], acc[i][f], 0, 0, 0);
        }
    };

    int4 GA[2][4], GB[2][4];          // G[s&1] holds gathers for stage s
    h2 cwA[4], cwB[4];                // cw[tap&1]

    // prologue: meta tap0; A stage0; gathers stage0+stage1; commit stage0.
    computeMeta(0, cwA);
    stageA(0, 0);
    __builtin_amdgcn_sched_barrier(0);
    issue(0, GA);
    commitS(0, GA, cwA);              // compiler waits GA (drains stageA too)
    issue(1, GB);
    asm volatile("s_waitcnt vmcnt(8) lgkmcnt(0)" ::: "memory");
    __builtin_amdgcn_s_barrier();
    __builtin_amdgcn_sched_barrier(0);

// Stage ST: commit stage ST+1 from GC (issued at ST-1, full stage of slack),
// issue stage ST+2 into GI. cw ping-pong is static per 4-stage period.
#define BODY(ST, GC, GI, CWC, DOMETA, CWI)                                   \
    {                                                                        \
        int cur_ = (ST) & 1, nb_ = cur_ ^ 1;                                 \
        if ((ST) + 1 < 18) stageA(nb_, (ST) + 1);                            \
        __builtin_amdgcn_sched_barrier(0);                                   \
        if ((ST) + 2 < 18) {                                                 \
            if (DOMETA) computeMeta(((ST) + 2) >> 1, CWI);                   \
            issue((ST) + 2, GI);                                             \
        }                                                                    \
        mfmaSec(cur_);                                                       \
        if ((ST) + 1 < 18) commitS(nb_, GC, CWC);                            \
        if ((ST) + 2 < 18) {                                                 \
            asm volatile("s_waitcnt vmcnt(8) lgkmcnt(0)" ::: "memory");      \
        } else {                                                             \
            asm volatile("s_waitcnt vmcnt(0) lgkmcnt(0)" ::: "memory");      \
        }                                                                    \
        __builtin_amdgcn_s_barrier();                                        \
        __builtin_amdgcn_sched_barrier(0);                                   \
    }

    for (int su = 0; su < 4; su++) {
        int st = su << 2;
        BODY(st,     GB, GA, cwA, 1, cwB);
        BODY(st + 1, GA, GB, cwB, 0, cwB);
        BODY(st + 2, GB, GA, cwB, 1, cwA);
        BODY(st + 3, GA, GB, cwA, 0, cwA);
    }
    BODY(16, GB, GA, cwA, 0, cwA);
    BODY(17, GA, GB, cwA, 0, cwA);
#undef BODY

    // epilogue: C layout col(p)=lane&15, row(o)=(lane>>4)*4+reg
    #pragma unroll
    for (int i = 0; i < 4; i++) {
        #pragma unroll
        for (int r = 0; r < 4; r++) {
            int o = wm * 64 + i * 16 + lq * 4 + r;
            float bv = bias[o];
            float* orow = out + (size_t)(b * COUT_ + o) * HWp + p0 + ns * 32 + lm;
            #pragma unroll
            for (int f = 0; f < 2; f++)
                orow[f * 16] = acc[i][f][r] + bv;
        }
    }
}

extern "C" void kernel_launch(void* const* d_in, const int* in_sizes, int n_in,
                              void* d_out, int out_size, void* d_ws, size_t ws_size,
                              hipStream_t stream) {
    const float* x     = (const float*)d_in[0];
    const float* w_off = (const float*)d_in[1];
    const float* b_off = (const float*)d_in[2];
    const float* w     = (const float*)d_in[3];
    const float* bias  = (const float*)d_in[4];
    float* out = (float*)d_out;

    char* ws = (char*)d_ws;
    ushort* xt   = (ushort*)ws;                          // 8 MiB (f16 NHWC)
    ushort* w_t2 = (ushort*)(ws + 8388608);              // 294912 B (f16 frag order)
    float4* der  = (float4*)(ws + 8683520);              // 512 KiB {sy,sx,sc1,sc2}/pos

    prep_offsets_kernel<<<1344, 256, 0, stream>>>(x, w, w_off, b_off,
                                                  xt, w_t2, der);
    deform_gemm_mfma<<<256, 512, 0, stream>>>(xt, w_t2, bias, der, out);
}

// Round 4
// 116.007 us; speedup vs baseline: 1.0597x; 1.0007x over previous
//
#include <hip/hip_runtime.h>

#define Wd 64
#define Hd 64
#define HWp 4096
#define CIN_ 128
#define COUT_ 128

typedef _Float16 f16;
typedef _Float16 h2    __attribute__((ext_vector_type(2)));
typedef _Float16 f16x8 __attribute__((ext_vector_type(8)));
typedef float f32x4    __attribute__((ext_vector_type(4)));

__device__ inline ushort f2h(float f) {
    f16 h = (f16)f;
    return __builtin_bit_cast(ushort, h);
}
__device__ inline h2 gb(const int4& g, int d) {
    return __builtin_bit_cast(h2, (&g.x)[d]);
}
__device__ inline h2 dup(float f) {
    f16 h = (f16)f;
    h2 r; r[0] = h; r[1] = h;
    return r;
}
struct H8 { h2 r[4]; };

// ---------------------------------------------------------------------------
// K_prep (1344 blocks):
//   blk 0..255    : transpose x NCHW f32 -> xt[b][yx][c] f16
//   blk 256..831  : repack main w -> f16 w_t2 in MFMA A-fragment order
//   blk 832..1343 : offset conv (4 used ch) -> der[b][p] = {sy,sx,sc1,sc2}
// ---------------------------------------------------------------------------
__global__ __launch_bounds__(256) void prep_offsets_kernel(
    const float* __restrict__ x, const float* __restrict__ w,
    const float* __restrict__ w_off, const float* __restrict__ b_off,
    ushort* __restrict__ xt, ushort* __restrict__ w_t2,
    float4* __restrict__ der)
{
    __shared__ char smem[34816];
    int blk = blockIdx.x;
    int t = threadIdx.x;

    if (blk < 256) {
        ushort* tile = (ushort*)smem;                 // [128][136]
        int b = blk >> 5, yx0 = (blk & 31) << 7;
        const float* xb = x + (size_t)b * CIN_ * HWp + yx0;
        int lanelo = t & 31, grp = t >> 5;
        #pragma unroll
        for (int i = 0; i < 4; i++) {
            int cbase = i * 32 + grp * 4;
            float4 v0 = *(const float4*)(xb + (size_t)(cbase + 0) * HWp + lanelo * 4);
            float4 v1 = *(const float4*)(xb + (size_t)(cbase + 1) * HWp + lanelo * 4);
            float4 v2 = *(const float4*)(xb + (size_t)(cbase + 2) * HWp + lanelo * 4);
            float4 v3 = *(const float4*)(xb + (size_t)(cbase + 3) * HWp + lanelo * 4);
            ushort4 u;
            u.x = f2h(v0.x); u.y = f2h(v1.x); u.z = f2h(v2.x); u.w = f2h(v3.x);
            *(ushort4*)&tile[(lanelo * 4 + 0) * 136 + cbase] = u;
            u.x = f2h(v0.y); u.y = f2h(v1.y); u.z = f2h(v2.y); u.w = f2h(v3.y);
            *(ushort4*)&tile[(lanelo * 4 + 1) * 136 + cbase] = u;
            u.x = f2h(v0.z); u.y = f2h(v1.z); u.z = f2h(v2.z); u.w = f2h(v3.z);
            *(ushort4*)&tile[(lanelo * 4 + 2) * 136 + cbase] = u;
            u.x = f2h(v0.w); u.y = f2h(v1.w); u.z = f2h(v2.w); u.w = f2h(v3.w);
            *(ushort4*)&tile[(lanelo * 4 + 3) * 136 + cbase] = u;
        }
        __syncthreads();
        ushort* dst = xt + ((size_t)b * HWp + yx0) * CIN_;
        int c8 = (t & 15) * 8, yxg = t >> 4;
        #pragma unroll
        for (int i = 0; i < 8; i++) {
            int yxl = i * 16 + yxg;
            int4 v = *(int4*)&tile[yxl * 136 + c8];
            *(int4*)(dst + (size_t)yxl * CIN_ + c8) = v;
        }
    } else if (blk < 832) {
        int i = (blk - 256) * 256 + t;               // 147456 total
        int j    = i & 7;
        int lane = (i >> 3) & 63;
        int ii   = (i >> 9) & 3;
        int wm   = (i >> 11) & 1;
        int s    = i >> 12;
        int o = wm * 64 + ii * 16 + (lane & 15);
        int c = (s & 3) * 32 + (lane >> 4) * 8 + j;
        int k = s >> 2;
        w_t2[i] = f2h(w[o * 1152 + c * 9 + k]);
    } else {
        float* wl   = (float*)smem;                   // 4608 f
        float* part = (float*)(smem + 18432);         // 1024 f
        int blk2 = blk - 832;
        int b = blk2 >> 6;
        int h = blk2 & 63;

        for (int i = t; i < 4608; i += 256) {
            int j = i / 1152;
            int r = i - j * 1152;                     // c*9 + tap
            wl[r * 4 + j] = w_off[i];
        }
        __syncthreads();

        int pi = t & 63, cc = t >> 6;
        const float* xb = x + (size_t)(b * CIN_ + cc * 32) * HWp;

        int idx9[9];
        float msk9[9];
        #pragma unroll
        for (int dy = 0; dy < 3; dy++) {
            int hy = h + dy - 1;
            int hyc = min(max(hy, 0), Hd - 1);
            bool vr = (hy >= 0) && (hy < Hd);
            #pragma unroll
            for (int dx = 0; dx < 3; dx++) {
                int wx = pi + dx - 1;
                int wxc = min(max(wx, 0), Wd - 1);
                bool v = vr && (wx >= 0) && (wx < Wd);
                idx9[dy * 3 + dx] = hyc * Wd + wxc;
                msk9[dy * 3 + dx] = v ? 1.0f : 0.0f;
            }
        }

        float o0 = 0.f, o1 = 0.f, o2 = 0.f, o3 = 0.f;
        #pragma unroll 4
        for (int c = 0; c < 32; c++) {
            const float* xp = xb + c * HWp;
            const float* wc = &wl[(cc * 32 + c) * 36];
            float xv[9];
            #pragma unroll
            for (int tp = 0; tp < 9; tp++) xv[tp] = xp[idx9[tp]] * msk9[tp];
            #pragma unroll
            for (int tp = 0; tp < 9; tp++) {
                float4 wj = *(const float4*)&wc[tp * 4];
                o0 += xv[tp] * wj.x; o1 += xv[tp] * wj.y;
                o2 += xv[tp] * wj.z; o3 += xv[tp] * wj.w;
            }
        }
        part[t * 4 + 0] = o0;
        part[t * 4 + 1] = o1;
        part[t * 4 + 2] = o2;
        part[t * 4 + 3] = o3;
        __syncthreads();

        if (t < 64) {
            float s0 = b_off[0], s1 = b_off[1], s2 = b_off[2], s3 = b_off[3];
            #pragma unroll
            for (int q = 0; q < 4; q++) {
                s0 += part[(q * 64 + t) * 4 + 0];
                s1 += part[(q * 64 + t) * 4 + 1];
                s2 += part[(q * 64 + t) * 4 + 2];
                s3 += part[(q * 64 + t) * 4 + 3];
            }
            float4 d;
            d.x = s0;
            d.y = s1;
            d.z = fmaxf(s2, 0.f) + 1.f;
            d.w = fmaxf(s3, 0.f) + 1.f;
            der[(size_t)b * HWp + h * Wd + t] = d;
        }
    }
}

// ---------------------------------------------------------------------------
// K3: fused gather + f16 MFMA GEMM, BK=64 stages, depth-2 gather prefetch.
// (Unchanged re-submission; rounds 2-3 were lost to broker timeouts.)
//  - b = blk&7 (XCD swizzle: each XCD's L2 serves one b -> xt slice resident)
//  - 9-tap bilinear meta computed ONCE into LDS tables (MI byte-offsets,
//    MW dup-f16 weights); per-stage meta cost = 2 broadcast ds_read_b128 +
//    4 int adds every other stage (was ~60 VALU).
//  - setprio(1) around MFMA cluster; nontemporal epilogue stores.
// ---------------------------------------------------------------------------
__global__ __launch_bounds__(512, 1) void deform_gemm_mfma(
    const ushort* __restrict__ xt, const ushort* __restrict__ w_t2,
    const float* __restrict__ bias, const float4* __restrict__ der,
    float* __restrict__ out)
{
    __shared__ ushort A_lds[2][2][4096];      // 32 KiB
    __shared__ ushort S_lds[2][2][128 * 40];  // 40 KiB
    __shared__ int4 MI[9][128];               // 18 KiB corner byte-offsets
    __shared__ int4 MW[9][128];               // 18 KiB dup-f16 weights (H8)

    int t = threadIdx.x;
    int b = blockIdx.x & 7;                   // XCD-local batch
    int rp = blockIdx.x >> 3;
    int p0 = rp << 7;
    const char* xtb = (const char*)(xt + (size_t)b * HWp * CIN_);

    int p  = t >> 2;                 // 0..127 position in tile
    int c8 = (t & 3) << 3;           // channel offset in 32-chunk
    int c8b = c8 * 2;                // bytes

    int wv = t >> 6, lane = t & 63;
    int wm = wv & 1, ns = wv >> 1;   // M-half, N-32-seg (0..3)
    int lm = lane & 15, lq = lane >> 4;

    f32x4 acc[4][2] = {};

    // ---- one-time meta: 4 threads per p split the 9 taps -------------------
    {
        int pg = p0 + p;
        float fh = (float)(pg >> 6), fp = (float)(pg & 63);
        float4 dv = der[(size_t)b * HWp + pg];   // {sy, sx, sc1, sc2}
        for (int k = (t & 3); k < 9; k += 4) {
            int ky = (k * 11) >> 5;              // k/3 for 0..8
            int kx = k - ky * 3;
            float by = (float)(ky - 1), bx = (float)(kx - 1);
            bool corner = (ky != 1) && (kx != 1);
            bool edge = (ky != 1) ^ (kx != 1);
            float sk = corner ? dv.z : (edge ? dv.w : 0.0f);
            float py = fh + by * sk + dv.x;
            float px = fp + bx * sk + dv.y;
            float y0f = floorf(py), x0f = floorf(px);
            float wy = py - y0f, wx = px - x0f;
            int y0 = (int)y0f, x0 = (int)x0f;
            int y1 = y0 + 1, x1 = x0 + 1;
            float vy0 = (y0 >= 0 && y0 < Hd) ? 1.f : 0.f;
            float vy1 = (y1 >= 0 && y1 < Hd) ? 1.f : 0.f;
            float vx0 = (x0 >= 0 && x0 < Wd) ? 1.f : 0.f;
            float vx1 = (x1 >= 0 && x1 < Wd) ? 1.f : 0.f;
            int cy0 = min(max(y0, 0), Hd - 1), cy1 = min(max(y1, 0), Hd - 1);
            int cx0 = min(max(x0, 0), Wd - 1), cx1 = min(max(x1, 0), Wd - 1);
            int4 ii;
            ii.x = (cy0 * Wd + cx0) << 8;        // * CIN_ * 2 bytes
            ii.y = (cy0 * Wd + cx1) << 8;
            ii.z = (cy1 * Wd + cx0) << 8;
            ii.w = (cy1 * Wd + cx1) << 8;
            MI[k][p] = ii;
            H8 hw;
            hw.r[0] = dup((1.f - wy) * (1.f - wx) * vy0 * vx0);
            hw.r[1] = dup((1.f - wy) * wx * vy0 * vx1);
            hw.r[2] = dup(wy * (1.f - wx) * vy1 * vx0);
            hw.r[3] = dup(wy * wx * vy1 * vx1);
            MW[k][p] = __builtin_bit_cast(int4, hw);
        }
    }
    __syncthreads();

    int vo0, vo1, vo2, vo3;          // gather byte offsets (current tap)

    // async A staging: stage st covers w_t2 ushorts [st*8192, st*8192+8192)
    auto stageA = [&](int buf, int st) {
        const ushort* src = w_t2 + (size_t)st * 8192;
        #pragma unroll
        for (int cc = 0; cc < 2; cc++) {
            const ushort* g = src + cc * 4096 + wv * 512 + lane * 8;
            ushort* l = &A_lds[buf][cc][wv * 512];
            __builtin_amdgcn_global_load_lds(
                (const __attribute__((address_space(1))) unsigned int*)g,
                (__attribute__((address_space(3))) unsigned int*)l, 16, 0, 0);
        }
    };

    auto issue = [&](int st, int4 (&G)[2][4]) {
        #pragma unroll
        for (int cc = 0; cc < 2; cc++) {
            int q = (2 * st + cc) & 3;
            G[cc][0] = *(const int4*)(xtb + (vo0 + q * 64));
            G[cc][1] = *(const int4*)(xtb + (vo1 + q * 64));
            G[cc][2] = *(const int4*)(xtb + (vo2 + q * 64));
            G[cc][3] = *(const int4*)(xtb + (vo3 + q * 64));
        }
    };
    auto commitS = [&](int buf, const int4 (&G)[2][4], const H8& cw) {
        #pragma unroll
        for (int cc = 0; cc < 2; cc++) {
            H8 tmp;
            #pragma unroll
            for (int d = 0; d < 4; d++) {
                h2 r = gb(G[cc][0], d) * cw.r[0];
                r = gb(G[cc][1], d) * cw.r[1] + r;
                r = gb(G[cc][2], d) * cw.r[2] + r;
                r = gb(G[cc][3], d) * cw.r[3] + r;
                tmp.r[d] = r;
            }
            *(int4*)&S_lds[buf][cc][p * 40 + c8] = __builtin_bit_cast(int4, tmp);
        }
    };
    auto mfmaSec = [&](int cur) {
        #pragma unroll
        for (int cc = 0; cc < 2; cc++) {
            f16x8 af[4], bfr[2];
            #pragma unroll
            for (int i = 0; i < 4; i++)
                af[i] = *(const f16x8*)&A_lds[cur][cc][(wm * 4 + i) * 512 + lane * 8];
            #pragma unroll
            for (int f = 0; f < 2; f++)
                bfr[f] = *(const f16x8*)&S_lds[cur][cc][(ns * 32 + f * 16 + lm) * 40 + lq * 8];
            #pragma unroll
            for (int i = 0; i < 4; i++)
                #pragma unroll
                for (int f = 0; f < 2; f++)
                    acc[i][f] = __builtin_amdgcn_mfma_f32_16x16x32_f16(
                        af[i], bfr[f], acc[i][f], 0, 0, 0);
        }
    };

    int4 GA[2][4], GB[2][4];          // G[s&1] holds gathers for stage s
    H8 cwA, cwB;
    int4 idxN;

    // prologue: A stage0; gathers stage0+stage1 (tap 0); commit stage0.
    stageA(0, 0);
    __builtin_amdgcn_sched_barrier(0);
    {
        int4 i0 = MI[0][p];
        vo0 = i0.x + c8b; vo1 = i0.y + c8b; vo2 = i0.z + c8b; vo3 = i0.w + c8b;
    }
    issue(0, GA);
    cwA = __builtin_bit_cast(H8, MW[0][p]);
    commitS(0, GA, cwA);              // compiler waits GA (drains stageA too)
    issue(1, GB);
    idxN = MI[1][p];                  // addrs for stages 2,3 (tap 1)
    asm volatile("s_waitcnt vmcnt(8) lgkmcnt(0)" ::: "memory");
    __builtin_amdgcn_s_barrier();
    __builtin_amdgcn_sched_barrier(0);

// Stage ST: commit stage ST+1 from GC (issued at ST-1), issue ST+2 into GI.
// DORD=1 on even stages: refresh gather addrs from idxN, then reload
// idxN (tap+2) and CWR (weights tap+1) from the LDS tables (clamped; the
// clamped tail reads are never consumed).
#define BODY(ST, GC, GI, CWC, CWR, DORD)                                     \
    {                                                                        \
        int cur_ = (ST) & 1, nb_ = cur_ ^ 1;                                 \
        if ((ST) + 1 < 18) stageA(nb_, (ST) + 1);                            \
        __builtin_amdgcn_sched_barrier(0);                                   \
        if ((ST) + 2 < 18) {                                                 \
            if (DORD) {                                                      \
                vo0 = idxN.x + c8b; vo1 = idxN.y + c8b;                      \
                vo2 = idxN.z + c8b; vo3 = idxN.w + c8b;                      \
            }                                                                \
            issue((ST) + 2, GI);                                             \
        }                                                                    \
        if (DORD) {                                                          \
            idxN = MI[min(((ST) >> 1) + 2, 8)][p];                           \
            CWR = __builtin_bit_cast(H8, MW[min(((ST) >> 1) + 1, 8)][p]);    \
        }                                                                    \
        __builtin_amdgcn_s_setprio(1);                                       \
        mfmaSec(cur_);                                                       \
        __builtin_amdgcn_s_setprio(0);                                       \
        if ((ST) + 1 < 18) commitS(nb_, GC, CWC);                            \
        if ((ST) + 2 < 18) {                                                 \
            asm volatile("s_waitcnt vmcnt(8) lgkmcnt(0)" ::: "memory");      \
        } else {                                                             \
            asm volatile("s_waitcnt vmcnt(0) lgkmcnt(0)" ::: "memory");      \
        }                                                                    \
        __builtin_amdgcn_s_barrier();                                        \
        __builtin_amdgcn_sched_barrier(0);                                   \
    }

    for (int su = 0; su < 4; su++) {
        int st = su << 2;
        BODY(st,     GB, GA, cwA, cwB, 1);
        BODY(st + 1, GA, GB, cwB, cwB, 0);
        BODY(st + 2, GB, GA, cwB, cwA, 1);
        BODY(st + 3, GA, GB, cwA, cwA, 0);
    }
    BODY(16, GB, GA, cwA, cwB, 1);
    BODY(17, GA, GB, cwB, cwB, 0);
#undef BODY

    // epilogue: C layout col(p)=lane&15, row(o)=(lane>>4)*4+reg
    #pragma unroll
    for (int i = 0; i < 4; i++) {
        #pragma unroll
        for (int r = 0; r < 4; r++) {
            int o = wm * 64 + i * 16 + lq * 4 + r;
            float bv = bias[o];
            float* orow = out + (size_t)(b * COUT_ + o) * HWp + p0 + ns * 32 + lm;
            #pragma unroll
            for (int f = 0; f < 2; f++)
                __builtin_nontemporal_store(acc[i][f][r] + bv, &orow[f * 16]);
        }
    }
}

extern "C" void kernel_launch(void* const* d_in, const int* in_sizes, int n_in,
                              void* d_out, int out_size, void* d_ws, size_t ws_size,
                              hipStream_t stream) {
    const float* x     = (const float*)d_in[0];
    const float* w_off = (const float*)d_in[1];
    const float* b_off = (const float*)d_in[2];
    const float* w     = (const float*)d_in[3];
    const float* bias  = (const float*)d_in[4];
    float* out = (float*)d_out;

    char* ws = (char*)d_ws;
    ushort* xt   = (ushort*)ws;                          // 8 MiB (f16 NHWC)
    ushort* w_t2 = (ushort*)(ws + 8388608);              // 294912 B (f16 frag order)
    float4* der  = (float4*)(ws + 8683520);              // 512 KiB {sy,sx,sc1,sc2}/pos

    prep_offsets_kernel<<<1344, 256, 0, stream>>>(x, w, w_off, b_off,
                                                  xt, w_t2, der);
    deform_gemm_mfma<<<256, 512, 0, stream>>>(xt, w_t2, bias, der, out);
}

// Round 5
// 114.583 us; speedup vs baseline: 1.0729x; 1.0124x over previous
//
#include <hip/hip_runtime.h>

#define Wd 64
#define Hd 64
#define HWp 4096
#define CIN_ 128
#define COUT_ 128

typedef _Float16 f16;
typedef _Float16 h2    __attribute__((ext_vector_type(2)));
typedef _Float16 f16x8 __attribute__((ext_vector_type(8)));
typedef float f32x4    __attribute__((ext_vector_type(4)));

__device__ inline ushort f2h(float f) {
    f16 h = (f16)f;
    return __builtin_bit_cast(ushort, h);
}
__device__ inline h2 gb(const int4& g, int d) {
    return __builtin_bit_cast(h2, (&g.x)[d]);
}
__device__ inline h2 dup(float f) {
    f16 h = (f16)f;
    h2 r; r[0] = h; r[1] = h;
    return r;
}
struct H8 { h2 r[4]; };

// ---------------------------------------------------------------------------
// K_prep (1344 blocks): unchanged.
//   blk 0..255    : transpose x NCHW f32 -> xt[b][yx][c] f16
//   blk 256..831  : repack main w -> f16 w_t2 in MFMA A-fragment order
//   blk 832..1343 : offset conv (4 used ch) -> der[b][p] = {sy,sx,sc1,sc2}
// ---------------------------------------------------------------------------
__global__ __launch_bounds__(256) void prep_offsets_kernel(
    const float* __restrict__ x, const float* __restrict__ w,
    const float* __restrict__ w_off, const float* __restrict__ b_off,
    ushort* __restrict__ xt, ushort* __restrict__ w_t2,
    float4* __restrict__ der)
{
    __shared__ char smem[34816];
    int blk = blockIdx.x;
    int t = threadIdx.x;

    if (blk < 256) {
        ushort* tile = (ushort*)smem;                 // [128][136]
        int b = blk >> 5, yx0 = (blk & 31) << 7;
        const float* xb = x + (size_t)b * CIN_ * HWp + yx0;
        int lanelo = t & 31, grp = t >> 5;
        #pragma unroll
        for (int i = 0; i < 4; i++) {
            int cbase = i * 32 + grp * 4;
            float4 v0 = *(const float4*)(xb + (size_t)(cbase + 0) * HWp + lanelo * 4);
            float4 v1 = *(const float4*)(xb + (size_t)(cbase + 1) * HWp + lanelo * 4);
            float4 v2 = *(const float4*)(xb + (size_t)(cbase + 2) * HWp + lanelo * 4);
            float4 v3 = *(const float4*)(xb + (size_t)(cbase + 3) * HWp + lanelo * 4);
            ushort4 u;
            u.x = f2h(v0.x); u.y = f2h(v1.x); u.z = f2h(v2.x); u.w = f2h(v3.x);
            *(ushort4*)&tile[(lanelo * 4 + 0) * 136 + cbase] = u;
            u.x = f2h(v0.y); u.y = f2h(v1.y); u.z = f2h(v2.y); u.w = f2h(v3.y);
            *(ushort4*)&tile[(lanelo * 4 + 1) * 136 + cbase] = u;
            u.x = f2h(v0.z); u.y = f2h(v1.z); u.z = f2h(v2.z); u.w = f2h(v3.z);
            *(ushort4*)&tile[(lanelo * 4 + 2) * 136 + cbase] = u;
            u.x = f2h(v0.w); u.y = f2h(v1.w); u.z = f2h(v2.w); u.w = f2h(v3.w);
            *(ushort4*)&tile[(lanelo * 4 + 3) * 136 + cbase] = u;
        }
        __syncthreads();
        ushort* dst = xt + ((size_t)b * HWp + yx0) * CIN_;
        int c8 = (t & 15) * 8, yxg = t >> 4;
        #pragma unroll
        for (int i = 0; i < 8; i++) {
            int yxl = i * 16 + yxg;
            int4 v = *(int4*)&tile[yxl * 136 + c8];
            *(int4*)(dst + (size_t)yxl * CIN_ + c8) = v;
        }
    } else if (blk < 832) {
        int i = (blk - 256) * 256 + t;               // 147456 total
        int j    = i & 7;
        int lane = (i >> 3) & 63;
        int ii   = (i >> 9) & 3;
        int wm   = (i >> 11) & 1;
        int s    = i >> 12;
        int o = wm * 64 + ii * 16 + (lane & 15);
        int c = (s & 3) * 32 + (lane >> 4) * 8 + j;
        int k = s >> 2;
        w_t2[i] = f2h(w[o * 1152 + c * 9 + k]);
    } else {
        float* wl   = (float*)smem;                   // 4608 f
        float* part = (float*)(smem + 18432);         // 1024 f
        int blk2 = blk - 832;
        int b = blk2 >> 6;
        int h = blk2 & 63;

        for (int i = t; i < 4608; i += 256) {
            int j = i / 1152;
            int r = i - j * 1152;                     // c*9 + tap
            wl[r * 4 + j] = w_off[i];
        }
        __syncthreads();

        int pi = t & 63, cc = t >> 6;
        const float* xb = x + (size_t)(b * CIN_ + cc * 32) * HWp;

        int idx9[9];
        float msk9[9];
        #pragma unroll
        for (int dy = 0; dy < 3; dy++) {
            int hy = h + dy - 1;
            int hyc = min(max(hy, 0), Hd - 1);
            bool vr = (hy >= 0) && (hy < Hd);
            #pragma unroll
            for (int dx = 0; dx < 3; dx++) {
                int wx = pi + dx - 1;
                int wxc = min(max(wx, 0), Wd - 1);
                bool v = vr && (wx >= 0) && (wx < Wd);
                idx9[dy * 3 + dx] = hyc * Wd + wxc;
                msk9[dy * 3 + dx] = v ? 1.0f : 0.0f;
            }
        }

        float o0 = 0.f, o1 = 0.f, o2 = 0.f, o3 = 0.f;
        #pragma unroll 4
        for (int c = 0; c < 32; c++) {
            const float* xp = xb + c * HWp;
            const float* wc = &wl[(cc * 32 + c) * 36];
            float xv[9];
            #pragma unroll
            for (int tp = 0; tp < 9; tp++) xv[tp] = xp[idx9[tp]] * msk9[tp];
            #pragma unroll
            for (int tp = 0; tp < 9; tp++) {
                float4 wj = *(const float4*)&wc[tp * 4];
                o0 += xv[tp] * wj.x; o1 += xv[tp] * wj.y;
                o2 += xv[tp] * wj.z; o3 += xv[tp] * wj.w;
            }
        }
        part[t * 4 + 0] = o0;
        part[t * 4 + 1] = o1;
        part[t * 4 + 2] = o2;
        part[t * 4 + 3] = o3;
        __syncthreads();

        if (t < 64) {
            float s0 = b_off[0], s1 = b_off[1], s2 = b_off[2], s3 = b_off[3];
            #pragma unroll
            for (int q = 0; q < 4; q++) {
                s0 += part[(q * 64 + t) * 4 + 0];
                s1 += part[(q * 64 + t) * 4 + 1];
                s2 += part[(q * 64 + t) * 4 + 2];
                s3 += part[(q * 64 + t) * 4 + 3];
            }
            float4 d;
            d.x = s0;
            d.y = s1;
            d.z = fmaxf(s2, 0.f) + 1.f;
            d.w = fmaxf(s3, 0.f) + 1.f;
            der[(size_t)b * HWp + h * Wd + t] = d;
        }
    }
}

// ---------------------------------------------------------------------------
// K3: fused gather + f16 MFMA GEMM, BK=64 stages, depth-2 gather prefetch.
// THIS ROUND: 256-thread blocks (4 waves), N-tile 64, grid 512 -> LDS 70 KB
// -> 2 INDEPENDENT blocks per CU. Same 2 waves/SIMD but from blocks at
// different pipeline phases: one block's barrier/gather drain overlaps the
// other block's MFMA+LDS work (previously 1 block/CU = all waves stall at
// the same barrier; every instruction-level tweak was neutral because the
// per-stage critical path was exposed latency, not issue bandwidth).
// ---------------------------------------------------------------------------
__global__ __launch_bounds__(256, 2) void deform_gemm_mfma(
    const ushort* __restrict__ xt, const ushort* __restrict__ w_t2,
    const float* __restrict__ bias, const float4* __restrict__ der,
    float* __restrict__ out)
{
    __shared__ ushort A_lds[2][2][4096];      // 32 KiB (full M=128 x 64c)
    __shared__ ushort S_lds[2][2][64 * 40];   // 20 KiB
    __shared__ int4 MI[9][64];                // 9 KiB corner byte-offsets
    __shared__ int4 MW[9][64];                // 9 KiB dup-f16 weights (H8)

    int t = threadIdx.x;
    int b = blockIdx.x & 7;                   // XCD-local batch
    int rp = blockIdx.x >> 3;                 // 0..63
    int p0 = rp << 6;
    const char* xtb = (const char*)(xt + (size_t)b * HWp * CIN_);

    int p  = t >> 2;                 // 0..63 position in tile
    int c8 = (t & 3) << 3;           // channel offset in 32-chunk
    int c8b = c8 * 2;                // bytes

    int wv = t >> 6, lane = t & 63;  // 4 waves
    int wm = wv & 1, ns = wv >> 1;   // M-half, N-32-seg (0..1)
    int lm = lane & 15, lq = lane >> 4;

    f32x4 acc[4][2] = {};

    // ---- one-time meta: 4 threads per p split the 9 taps -------------------
    {
        int pg = p0 + p;
        float fh = (float)(pg >> 6), fp = (float)(pg & 63);
        float4 dv = der[(size_t)b * HWp + pg];   // {sy, sx, sc1, sc2}
        for (int k = (t & 3); k < 9; k += 4) {
            int ky = (k * 11) >> 5;              // k/3 for 0..8
            int kx = k - ky * 3;
            float by = (float)(ky - 1), bx = (float)(kx - 1);
            bool corner = (ky != 1) && (kx != 1);
            bool edge = (ky != 1) ^ (kx != 1);
            float sk = corner ? dv.z : (edge ? dv.w : 0.0f);
            float py = fh + by * sk + dv.x;
            float px = fp + bx * sk + dv.y;
            float y0f = floorf(py), x0f = floorf(px);
            float wy = py - y0f, wx = px - x0f;
            int y0 = (int)y0f, x0 = (int)x0f;
            int y1 = y0 + 1, x1 = x0 + 1;
            float vy0 = (y0 >= 0 && y0 < Hd) ? 1.f : 0.f;
            float vy1 = (y1 >= 0 && y1 < Hd) ? 1.f : 0.f;
            float vx0 = (x0 >= 0 && x0 < Wd) ? 1.f : 0.f;
            float vx1 = (x1 >= 0 && x1 < Wd) ? 1.f : 0.f;
            int cy0 = min(max(y0, 0), Hd - 1), cy1 = min(max(y1, 0), Hd - 1);
            int cx0 = min(max(x0, 0), Wd - 1), cx1 = min(max(x1, 0), Wd - 1);
            int4 ii;
            ii.x = (cy0 * Wd + cx0) << 8;        // * CIN_ * 2 bytes
            ii.y = (cy0 * Wd + cx1) << 8;
            ii.z = (cy1 * Wd + cx0) << 8;
            ii.w = (cy1 * Wd + cx1) << 8;
            MI[k][p] = ii;
            H8 hw;
            hw.r[0] = dup((1.f - wy) * (1.f - wx) * vy0 * vx0);
            hw.r[1] = dup((1.f - wy) * wx * vy0 * vx1);
            hw.r[2] = dup(wy * (1.f - wx) * vy1 * vx0);
            hw.r[3] = dup(wy * wx * vy1 * vx1);
            MW[k][p] = __builtin_bit_cast(int4, hw);
        }
    }
    __syncthreads();

    int vo0, vo1, vo2, vo3;          // gather byte offsets (current tap)

    // async A staging: stage st covers w_t2 ushorts [st*8192, st*8192+8192).
    // 4 waves x 2 rows each per chunk (row = 512 ushorts = 1 KiB).
    auto stageA = [&](int buf, int st) {
        const ushort* src = w_t2 + (size_t)st * 8192;
        #pragma unroll
        for (int cc = 0; cc < 2; cc++) {
            #pragma unroll
            for (int hrow = 0; hrow < 2; hrow++) {
                const ushort* g = src + cc * 4096 + (wv * 2 + hrow) * 512 + lane * 8;
                ushort* l = &A_lds[buf][cc][(wv * 2 + hrow) * 512];
                __builtin_amdgcn_global_load_lds(
                    (const __attribute__((address_space(1))) unsigned int*)g,
                    (__attribute__((address_space(3))) unsigned int*)l, 16, 0, 0);
            }
        }
    };

    auto issue = [&](int st, int4 (&G)[2][4]) {
        #pragma unroll
        for (int cc = 0; cc < 2; cc++) {
            int q = (2 * st + cc) & 3;
            G[cc][0] = *(const int4*)(xtb + (vo0 + q * 64));
            G[cc][1] = *(const int4*)(xtb + (vo1 + q * 64));
            G[cc][2] = *(const int4*)(xtb + (vo2 + q * 64));
            G[cc][3] = *(const int4*)(xtb + (vo3 + q * 64));
        }
    };
    auto commitS = [&](int buf, const int4 (&G)[2][4], const H8& cw) {
        #pragma unroll
        for (int cc = 0; cc < 2; cc++) {
            H8 tmp;
            #pragma unroll
            for (int d = 0; d < 4; d++) {
                h2 r = gb(G[cc][0], d) * cw.r[0];
                r = gb(G[cc][1], d) * cw.r[1] + r;
                r = gb(G[cc][2], d) * cw.r[2] + r;
                r = gb(G[cc][3], d) * cw.r[3] + r;
                tmp.r[d] = r;
            }
            *(int4*)&S_lds[buf][cc][p * 40 + c8] = __builtin_bit_cast(int4, tmp);
        }
    };
    auto mfmaSec = [&](int cur) {
        #pragma unroll
        for (int cc = 0; cc < 2; cc++) {
            f16x8 af[4], bfr[2];
            #pragma unroll
            for (int i = 0; i < 4; i++)
                af[i] = *(const f16x8*)&A_lds[cur][cc][(wm * 4 + i) * 512 + lane * 8];
            #pragma unroll
            for (int f = 0; f < 2; f++)
                bfr[f] = *(const f16x8*)&S_lds[cur][cc][(ns * 32 + f * 16 + lm) * 40 + lq * 8];
            #pragma unroll
            for (int i = 0; i < 4; i++)
                #pragma unroll
                for (int f = 0; f < 2; f++)
                    acc[i][f] = __builtin_amdgcn_mfma_f32_16x16x32_f16(
                        af[i], bfr[f], acc[i][f], 0, 0, 0);
        }
    };

    int4 GA[2][4], GB[2][4];          // G[s&1] holds gathers for stage s
    H8 cwA, cwB;
    int4 idxN;

    // prologue: A stage0; gathers stage0+stage1 (tap 0); commit stage0.
    stageA(0, 0);
    __builtin_amdgcn_sched_barrier(0);
    {
        int4 i0 = MI[0][p];
        vo0 = i0.x + c8b; vo1 = i0.y + c8b; vo2 = i0.z + c8b; vo3 = i0.w + c8b;
    }
    issue(0, GA);
    cwA = __builtin_bit_cast(H8, MW[0][p]);
    commitS(0, GA, cwA);              // compiler waits GA (drains stageA too)
    issue(1, GB);
    idxN = MI[1][p];                  // addrs for stages 2,3 (tap 1)
    asm volatile("s_waitcnt vmcnt(8) lgkmcnt(0)" ::: "memory");
    __builtin_amdgcn_s_barrier();
    __builtin_amdgcn_sched_barrier(0);

// Stage ST: commit stage ST+1 from GC (issued at ST-1), issue ST+2 into GI.
// DORD=1 on even stages: refresh gather addrs from idxN, then reload
// idxN (tap+2) and CWR (weights tap+1) from the LDS tables (clamped; the
// clamped tail reads are never consumed).
#define BODY(ST, GC, GI, CWC, CWR, DORD)                                     \
    {                                                                        \
        int cur_ = (ST) & 1, nb_ = cur_ ^ 1;                                 \
        if ((ST) + 1 < 18) stageA(nb_, (ST) + 1);                            \
        __builtin_amdgcn_sched_barrier(0);                                   \
        if ((ST) + 2 < 18) {                                                 \
            if (DORD) {                                                      \
                vo0 = idxN.x + c8b; vo1 = idxN.y + c8b;                      \
                vo2 = idxN.z + c8b; vo3 = idxN.w + c8b;                      \
            }                                                                \
            issue((ST) + 2, GI);                                             \
        }                                                                    \
        if (DORD) {                                                          \
            idxN = MI[min(((ST) >> 1) + 2, 8)][p];                           \
            CWR = __builtin_bit_cast(H8, MW[min(((ST) >> 1) + 1, 8)][p]);    \
        }                                                                    \
        __builtin_amdgcn_s_setprio(1);                                       \
        mfmaSec(cur_);                                                       \
        __builtin_amdgcn_s_setprio(0);                                       \
        if ((ST) + 1 < 18) commitS(nb_, GC, CWC);                            \
        if ((ST) + 2 < 18) {                                                 \
            asm volatile("s_waitcnt vmcnt(8) lgkmcnt(0)" ::: "memory");      \
        } else {                                                             \
            asm volatile("s_waitcnt vmcnt(0) lgkmcnt(0)" ::: "memory");      \
        }                                                                    \
        __builtin_amdgcn_s_barrier();                                        \
        __builtin_amdgcn_sched_barrier(0);                                   \
    }

    for (int su = 0; su < 4; su++) {
        int st = su << 2;
        BODY(st,     GB, GA, cwA, cwB, 1);
        BODY(st + 1, GA, GB, cwB, cwB, 0);
        BODY(st + 2, GB, GA, cwB, cwA, 1);
        BODY(st + 3, GA, GB, cwA, cwA, 0);
    }
    BODY(16, GB, GA, cwA, cwB, 1);
    BODY(17, GA, GB, cwB, cwB, 0);
#undef BODY

    // epilogue: C layout col(p)=lane&15, row(o)=(lane>>4)*4+reg
    #pragma unroll
    for (int i = 0; i < 4; i++) {
        #pragma unroll
        for (int r = 0; r < 4; r++) {
            int o = wm * 64 + i * 16 + lq * 4 + r;
            float bv = bias[o];
            float* orow = out + (size_t)(b * COUT_ + o) * HWp + p0 + ns * 32 + lm;
            #pragma unroll
            for (int f = 0; f < 2; f++)
                __builtin_nontemporal_store(acc[i][f][r] + bv, &orow[f * 16]);
        }
    }
}

extern "C" void kernel_launch(void* const* d_in, const int* in_sizes, int n_in,
                              void* d_out, int out_size, void* d_ws, size_t ws_size,
                              hipStream_t stream) {
    const float* x     = (const float*)d_in[0];
    const float* w_off = (const float*)d_in[1];
    const float* b_off = (const float*)d_in[2];
    const float* w     = (const float*)d_in[3];
    const float* bias  = (const float*)d_in[4];
    float* out = (float*)d_out;

    char* ws = (char*)d_ws;
    ushort* xt   = (ushort*)ws;                          // 8 MiB (f16 NHWC)
    ushort* w_t2 = (ushort*)(ws + 8388608);              // 294912 B (f16 frag order)
    float4* der  = (float4*)(ws + 8683520);              // 512 KiB {sy,sx,sc1,sc2}/pos

    prep_offsets_kernel<<<1344, 256, 0, stream>>>(x, w, w_off, b_off,
                                                  xt, w_t2, der);
    deform_gemm_mfma<<<512, 256, 0, stream>>>(xt, w_t2, bias, der, out);
}